// Round 14
// baseline (120.730 us; speedup 1.0000x reference)
//
#include <hip/hip_runtime.h>
#include <stdint.h>

#define T_DIM 64
#define IN_DIM 4096
#define OUT_DIM 8192
#define NGROUPS 16
#define GS 256
#define SPLITK 8
#define KCHUNK (IN_DIM / SPLITK)    // 512
#define BK 32                       // ints per row per stage (128B granule)
#define NSTAGES (KCHUNK / BK)       // 16
#define NTILE 256                   // output cols per block
#define WCOLS 32                    // output cols per wave (two B-frags)
#define OUT_ELEMS (T_DIM * OUT_DIM) // 524288
#define PART_OFF (1u << 20)         // partials at d_ws + 1MB
#define CNT_OFF  (16u << 20)        // counters at d_ws + 16MB

typedef __attribute__((ext_vector_type(4))) float f32x4;
typedef __attribute__((ext_vector_type(8))) __bf16 bf16x8;

__global__ void zero_kernel(float4* __restrict__ p, int n4) {
    int i = blockIdx.x * blockDim.x + threadIdx.x;
    if (i < n4) p[i] = make_float4(0.f, 0.f, 0.f, 0.f);
}

__device__ __forceinline__ void gld_lds16(const int* g, int* l) {
    __builtin_amdgcn_global_load_lds(
        (const __attribute__((address_space(1))) void*)g,
        (__attribute__((address_space(3))) void*)l, 16, 0, 0);
}

// Block = 8 waves (512 thr), N-tile = 256, K-chunk = 512 (SPLITK=8).
// K-loop is EXACTLY R11's best (33.5us): fused x-cvt prologue, wave-private
// double-buffered weight staging (4 gld_lds/stage), counted vmcnt(4), XOR
// swizzle chunk^(row&7), bf16 split-K partials.
// R14 CHANGE: split-K reduce fused via NO-SPIN "last block reduces":
// each block stores partials -> __threadfence (all threads) -> one
// fetch_add(ACQ_REL, agent) by thread 0; the 8th arriver (old==7) of each
// obase group reduces that group's 64 x 256 tile and exits. No polling ->
// none of R12's continuous acquire-invalidate fabric thrash (that was the
// 527 GB/s catastrophe: 224 spinners invalidating L2 all kernel long).
// grid = (32, SPLITK) = 256 blocks = 1/CU.
template<bool FUSED>
__global__ __launch_bounds__(512, 2)
void qgemm(const float* __restrict__ x,
           const int* __restrict__ qw, const float* __restrict__ qrange,
           const float* __restrict__ qmin, float* __restrict__ out,
           __bf16* __restrict__ bpart, unsigned int* __restrict__ cnt)
{
    __shared__ int xs[64 * 256];          // x panel: 64 rows x 1024B (64KB)
    __shared__ int wl[2][NTILE * BK];     // weights: 2 x 32KB double buffer

    const int lane  = threadIdx.x & 63;
    const int wv    = threadIdx.x >> 6;   // 0..7
    const int r     = lane & 15;          // fragment row/col index
    const int q4    = lane >> 4;          // k-slot (0..3)
    const int obase = blockIdx.x * NTILE;
    const int ks    = blockIdx.y;
    const int kbase = ks * KCHUNK;
    const int rl0   = wv * WCOLS + r;     // local weight row, frag n=0
    const int o0    = obase + rl0;        // output col, frag n=0
    const int o1    = o0 + 16;            // output col, frag n=1

    // 2 quant groups per K-chunk (KCHUNK=512, GS=256); group = s>>3
    float sc[2][2], mi[2][2];             // [n][g]
    #pragma unroll
    for (int g = 0; g < 2; ++g) {
        sc[0][g] = qrange[o0 * NGROUPS + ks * 2 + g];
        mi[0][g] = qmin[o0 * NGROUPS + ks * 2 + g];
        sc[1][g] = qrange[o1 * NGROUPS + ks * 2 + g];
        mi[1][g] = qmin[o1 * NGROUPS + ks * 2 + g];
    }

    f32x4 acc[4][2] = {};

    // ---- weight staging: wave's 32 rows x 128B = 4 gld_lds (8 rows each).
    auto stage_w = [&](int s, int b) {
        #pragma unroll
        for (int i = 0; i < 4; ++i) {
            const int row = wv * WCOLS + i * 8 + (lane >> 3);
            const int c   = (lane & 7) ^ (row & 7);
            const int* gp = qw + (size_t)(obase + row) * IN_DIM + kbase + s * BK
                               + (c << 2);
            gld_lds16(gp, &wl[b][(wv * WCOLS + i * 8) * BK]);
        }
    };
    stage_w(0, 0);   // in flight during the x prologue below

    // ---- x prologue (fused cvt): thread t owns row t>>3, 8 logical 16B
    // chunks lc = (t&7)*8 + i (full 64-chunk coverage); phys = lc ^ (row&7).
    {
        const int row  = threadIdx.x >> 3;        // 0..63
        const int cseg = threadIdx.x & 7;
        const float* xr = x + (size_t)row * IN_DIM + kbase;
        #pragma unroll
        for (int i = 0; i < 8; ++i) {
            const int lc = cseg * 8 + i;          // logical 16B chunk, 0..63
            float4 f0 = *(const float4*)(xr + lc * 8);
            float4 f1 = *(const float4*)(xr + lc * 8 + 4);
            bf16x8 t;
            t[0] = (__bf16)f0.x; t[1] = (__bf16)f0.y; t[2] = (__bf16)f0.z; t[3] = (__bf16)f0.w;
            t[4] = (__bf16)f1.x; t[5] = (__bf16)f1.y; t[6] = (__bf16)f1.z; t[7] = (__bf16)f1.w;
            const int pc = lc ^ (row & 7);        // phys chunk (swizzled)
            *(int4*)&xs[row * 256 + pc * 4] = *(int4*)&t;
        }
    }

    __syncthreads();   // x panel + w(0) visible to all waves

    auto compute = [&](int s, int b) {
        const int g = s >> 3;
        bf16x8 a[4];
        #pragma unroll
        for (int m = 0; m < 4; ++m) {
            const int rr = m * 16 + r;
            const int p  = (s * 4 + q4) ^ (rr & 7);   // phys 16B chunk
            a[m] = *(const bf16x8*)&xs[rr * 256 + p * 4];
        }
        #pragma unroll
        for (int n = 0; n < 2; ++n) {
            const int rl = rl0 + n * 16;
            const int p0 = ((q4 * 2    ) ^ (rl & 7)) * 4;
            const int p1 = ((q4 * 2 + 1) ^ (rl & 7)) * 4;
            int4 c0 = *(const int4*)&wl[b][rl * BK + p0];
            int4 c1 = *(const int4*)&wl[b][rl * BK + p1];
            const float s0 = sc[n][g], m0 = mi[n][g];
            bf16x8 bfr;
            bfr[0] = (__bf16)((float)c0.x * s0 + m0);
            bfr[1] = (__bf16)((float)c0.y * s0 + m0);
            bfr[2] = (__bf16)((float)c0.z * s0 + m0);
            bfr[3] = (__bf16)((float)c0.w * s0 + m0);
            bfr[4] = (__bf16)((float)c1.x * s0 + m0);
            bfr[5] = (__bf16)((float)c1.y * s0 + m0);
            bfr[6] = (__bf16)((float)c1.z * s0 + m0);
            bfr[7] = (__bf16)((float)c1.w * s0 + m0);
            #pragma unroll
            for (int m = 0; m < 4; ++m)
                acc[m][n] = __builtin_amdgcn_mfma_f32_16x16x32_bf16(a[m], bfr, acc[m][n], 0, 0, 0);
        }
    };

    #pragma unroll
    for (int s = 0; s < NSTAGES; ++s) {
        if (s + 1 < NSTAGES) {
            stage_w(s + 1, (s + 1) & 1);   // 4 gld_lds for next stage
            asm volatile("s_waitcnt vmcnt(4)" ::: "memory");
        } else {
            asm volatile("s_waitcnt vmcnt(0)" ::: "memory");
        }
        __builtin_amdgcn_sched_barrier(0);
        compute(s, s & 1);
    }

    // ---- write bf16 partials (plain stores)
    {
        __bf16* part = bpart + (size_t)ks * OUT_ELEMS;
        #pragma unroll
        for (int m = 0; m < 4; ++m) {
            #pragma unroll
            for (int j = 0; j < 4; ++j) {
                const int t = m * 16 + q4 * 4 + j;
                part[(size_t)t * OUT_DIM + o0] = (__bf16)acc[m][0][j];
                part[(size_t)t * OUT_DIM + o1] = (__bf16)acc[m][1][j];
            }
        }
    }

    if constexpr (FUSED) {
        // ---- no-spin last-arrival: 8th block of this obase group reduces.
        __shared__ unsigned winner;
        __threadfence();                  // device-scope release of partials
        __syncthreads();                  // all threads' stores + fences done
        if (threadIdx.x == 0) {
            unsigned old = __hip_atomic_fetch_add(&cnt[blockIdx.x], 1u,
                               __ATOMIC_ACQ_REL, __HIP_MEMORY_SCOPE_AGENT);
            winner = (old == (unsigned)(SPLITK - 1)) ? 1u : 0u;
        }
        __syncthreads();
        if (winner) {
            __threadfence();              // acquire side before partial loads
            // reduce this group's 64 rows x 256 cols (2048 vec8, 4/thread)
            #pragma unroll
            for (int v = 0; v < 4; ++v) {
                const int flat = threadIdx.x * 4 + v;      // 0..2047
                const int row  = flat >> 5;                // 0..63
                const int c8   = flat & 31;                // vec8 within 256
                const size_t off = (size_t)row * OUT_DIM + obase + c8 * 8;
                float s[8] = {};
                #pragma unroll
                for (int k = 0; k < SPLITK; ++k) {
                    bf16x8 pv = *(const bf16x8*)(bpart + (size_t)k * OUT_ELEMS + off);
                    #pragma unroll
                    for (int j = 0; j < 8; ++j) s[j] += (float)pv[j];
                }
                *(float4*)(out + off)     = make_float4(s[0], s[1], s[2], s[3]);
                *(float4*)(out + off + 4) = make_float4(s[4], s[5], s[6], s[7]);
            }
        }
    }
}

// standalone reduce (fallback path only)
__global__ void reduce_kernel(const __bf16* __restrict__ part, float* __restrict__ out, int n8) {
    int i = blockIdx.x * blockDim.x + threadIdx.x;
    if (i < n8) {
        float s[8] = {};
        #pragma unroll
        for (int k = 0; k < SPLITK; ++k) {
            bf16x8 v = *(const bf16x8*)(part + (size_t)k * OUT_ELEMS + (size_t)i * 8);
            #pragma unroll
            for (int j = 0; j < 8; ++j) s[j] += (float)v[j];
        }
        *(float4*)(out + (size_t)i * 8)     = make_float4(s[0], s[1], s[2], s[3]);
        *(float4*)(out + (size_t)i * 8 + 4) = make_float4(s[4], s[5], s[6], s[7]);
    }
}

extern "C" void kernel_launch(void* const* d_in, const int* in_sizes, int n_in,
                              void* d_out, int out_size, void* d_ws, size_t ws_size,
                              hipStream_t stream)
{
    const float* x      = (const float*)d_in[0];
    const int*   qw     = (const int*)d_in[1];
    const float* qrange = (const float*)d_in[2];
    const float* qmin   = (const float*)d_in[3];
    float* out = (float*)d_out;

    const size_t need = CNT_OFF + 32 * sizeof(unsigned int);

    if (ws_size >= need) {
        __bf16* part = (__bf16*)((char*)d_ws + PART_OFF);
        unsigned int* cnt = (unsigned int*)((char*)d_ws + CNT_OFF);
        hipMemsetAsync(cnt, 0, 32 * sizeof(unsigned int), stream);
        qgemm<true><<<dim3(OUT_DIM / NTILE, SPLITK), dim3(512), 0, stream>>>(
            x, qw, qrange, qmin, out, part, cnt);
    } else {
        // fallback: separate reduce kernel
        __bf16* part = (__bf16*)((char*)d_ws + PART_OFF);
        qgemm<false><<<dim3(OUT_DIM / NTILE, SPLITK), dim3(512), 0, stream>>>(
            x, qw, qrange, qmin, out, part, nullptr);
        const int n8 = OUT_ELEMS / 8;
        reduce_kernel<<<dim3(n8 / 256), dim3(256), 0, stream>>>(part, out, n8);
    }
}

// Round 15
// 33.461 us; speedup vs baseline: 3.6081x; 3.6081x over previous
//
#include <hip/hip_runtime.h>
#include <stdint.h>

#define T_DIM 64
#define IN_DIM 4096
#define OUT_DIM 8192
#define NGROUPS 16
#define GS 256
#define SPLITK 8
#define KCHUNK (IN_DIM / SPLITK)    // 512
#define BK 32                       // ints per row per stage (128B granule)
#define NSTAGES (KCHUNK / BK)       // 16
#define NTILE 256                   // output cols per block
#define WCOLS 32                    // output cols per wave (two B-frags)
#define OUT_ELEMS (T_DIM * OUT_DIM) // 524288
#define PART_OFF (1u << 20)         // partials at d_ws + 1MB

typedef __attribute__((ext_vector_type(4))) float f32x4;
typedef __attribute__((ext_vector_type(8))) __bf16 bf16x8;

__global__ void zero_kernel(float4* __restrict__ p, int n4) {
    int i = blockIdx.x * blockDim.x + threadIdx.x;
    if (i < n4) p[i] = make_float4(0.f, 0.f, 0.f, 0.f);
}

// sum 8 bf16 partial slices -> f32 output. thread i handles 8 elems.
__global__ void reduce_kernel(const __bf16* __restrict__ part, float* __restrict__ out, int n8) {
    int i = blockIdx.x * blockDim.x + threadIdx.x;
    if (i < n8) {
        float s[8] = {};
        #pragma unroll
        for (int k = 0; k < SPLITK; ++k) {
            bf16x8 v = *(const bf16x8*)(part + (size_t)k * OUT_ELEMS + (size_t)i * 8);
            #pragma unroll
            for (int j = 0; j < 8; ++j) s[j] += (float)v[j];
        }
        *(float4*)(out + (size_t)i * 8)     = make_float4(s[0], s[1], s[2], s[3]);
        *(float4*)(out + (size_t)i * 8 + 4) = make_float4(s[4], s[5], s[6], s[7]);
    }
}

__device__ __forceinline__ void gld_lds16(const int* g, int* l) {
    __builtin_amdgcn_global_load_lds(
        (const __attribute__((address_space(1))) void*)g,
        (__attribute__((address_space(3))) void*)l, 16, 0, 0);
}

// Block = 8 waves (512 thr), N-tile = 256, K-chunk = 512 (SPLITK=8).
// BEST-MEASURED STRUCTURE (R11, 33.5us — reverted to after R12/R14 proved
// cross-block fused epilogues collapse the memory fabric on this chip, and
// R13 proved depth-2 prefetch is null):
//  - fused x-cvt prologue: block stages its 64 x 512 x-panel straight from
//    the f32 input (L2/L3-resident) with in-register f32->bf16 cvt +
//    swizzled ds_write_b128; one __syncthreads total.
//  - wave-private double-buffered weight staging: 4 gld_lds per stage
//    (8 rows x 128B each), counted s_waitcnt vmcnt(4) -> next stage stays
//    in flight across compute(s); no barriers in the K-loop.
//  - XOR swizzle chunk^(row&7) on both LDS tiles (<=2-way banks, free),
//    applied at SOURCE addr for gld_lds (dest linear) and again on reads.
//  - bf16 split-K partials + separate reduce kernel (no atomics, no fences).
// qgemm moves ~174MB of loads at ~6.1 TB/s = 97% of the measured 6.29 TB/s
// streaming ceiling (m13). grid = (32, SPLITK) = 256 blocks = 1/CU.
template<bool PART>
__global__ __launch_bounds__(512, 2)
void qgemm(const float* __restrict__ x,
           const int* __restrict__ qw, const float* __restrict__ qrange,
           const float* __restrict__ qmin, float* __restrict__ out,
           __bf16* __restrict__ bpart)
{
    __shared__ int xs[64 * 256];          // x panel: 64 rows x 1024B (64KB)
    __shared__ int wl[2][NTILE * BK];     // weights: 2 x 32KB double buffer

    const int lane  = threadIdx.x & 63;
    const int wv    = threadIdx.x >> 6;   // 0..7
    const int r     = lane & 15;          // fragment row/col index
    const int q4    = lane >> 4;          // k-slot (0..3)
    const int obase = blockIdx.x * NTILE;
    const int ks    = blockIdx.y;
    const int kbase = ks * KCHUNK;
    const int rl0   = wv * WCOLS + r;     // local weight row, frag n=0
    const int o0    = obase + rl0;        // output col, frag n=0
    const int o1    = o0 + 16;            // output col, frag n=1

    // 2 quant groups per K-chunk (KCHUNK=512, GS=256); group = s>>3
    float sc[2][2], mi[2][2];             // [n][g]
    #pragma unroll
    for (int g = 0; g < 2; ++g) {
        sc[0][g] = qrange[o0 * NGROUPS + ks * 2 + g];
        mi[0][g] = qmin[o0 * NGROUPS + ks * 2 + g];
        sc[1][g] = qrange[o1 * NGROUPS + ks * 2 + g];
        mi[1][g] = qmin[o1 * NGROUPS + ks * 2 + g];
    }

    f32x4 acc[4][2] = {};

    // ---- weight staging: wave's 32 rows x 128B = 4 gld_lds (8 rows each).
    auto stage_w = [&](int s, int b) {
        #pragma unroll
        for (int i = 0; i < 4; ++i) {
            const int row = wv * WCOLS + i * 8 + (lane >> 3);
            const int c   = (lane & 7) ^ (row & 7);
            const int* gp = qw + (size_t)(obase + row) * IN_DIM + kbase + s * BK
                               + (c << 2);
            gld_lds16(gp, &wl[b][(wv * WCOLS + i * 8) * BK]);
        }
    };
    stage_w(0, 0);   // in flight during the x prologue below

    // ---- x prologue (fused cvt): thread t owns row t>>3, 8 logical 16B
    // chunks lc = (t&7)*8 + i (full 64-chunk coverage); phys = lc ^ (row&7).
    {
        const int row  = threadIdx.x >> 3;        // 0..63
        const int cseg = threadIdx.x & 7;
        const float* xr = x + (size_t)row * IN_DIM + kbase;
        #pragma unroll
        for (int i = 0; i < 8; ++i) {
            const int lc = cseg * 8 + i;          // logical 16B chunk, 0..63
            float4 f0 = *(const float4*)(xr + lc * 8);
            float4 f1 = *(const float4*)(xr + lc * 8 + 4);
            bf16x8 t;
            t[0] = (__bf16)f0.x; t[1] = (__bf16)f0.y; t[2] = (__bf16)f0.z; t[3] = (__bf16)f0.w;
            t[4] = (__bf16)f1.x; t[5] = (__bf16)f1.y; t[6] = (__bf16)f1.z; t[7] = (__bf16)f1.w;
            const int pc = lc ^ (row & 7);        // phys chunk (swizzled)
            *(int4*)&xs[row * 256 + pc * 4] = *(int4*)&t;
        }
    }

    __syncthreads();   // x panel + w(0) visible to all waves

    auto compute = [&](int s, int b) {
        const int g = s >> 3;
        bf16x8 a[4];
        #pragma unroll
        for (int m = 0; m < 4; ++m) {
            const int rr = m * 16 + r;
            const int p  = (s * 4 + q4) ^ (rr & 7);   // phys 16B chunk
            a[m] = *(const bf16x8*)&xs[rr * 256 + p * 4];
        }
        #pragma unroll
        for (int n = 0; n < 2; ++n) {
            const int rl = rl0 + n * 16;
            const int p0 = ((q4 * 2    ) ^ (rl & 7)) * 4;
            const int p1 = ((q4 * 2 + 1) ^ (rl & 7)) * 4;
            int4 c0 = *(const int4*)&wl[b][rl * BK + p0];
            int4 c1 = *(const int4*)&wl[b][rl * BK + p1];
            const float s0 = sc[n][g], m0 = mi[n][g];
            bf16x8 bfr;
            bfr[0] = (__bf16)((float)c0.x * s0 + m0);
            bfr[1] = (__bf16)((float)c0.y * s0 + m0);
            bfr[2] = (__bf16)((float)c0.z * s0 + m0);
            bfr[3] = (__bf16)((float)c0.w * s0 + m0);
            bfr[4] = (__bf16)((float)c1.x * s0 + m0);
            bfr[5] = (__bf16)((float)c1.y * s0 + m0);
            bfr[6] = (__bf16)((float)c1.z * s0 + m0);
            bfr[7] = (__bf16)((float)c1.w * s0 + m0);
            #pragma unroll
            for (int m = 0; m < 4; ++m)
                acc[m][n] = __builtin_amdgcn_mfma_f32_16x16x32_bf16(a[m], bfr, acc[m][n], 0, 0, 0);
        }
    };

    #pragma unroll
    for (int s = 0; s < NSTAGES; ++s) {
        if (s + 1 < NSTAGES) {
            stage_w(s + 1, (s + 1) & 1);   // 4 gld_lds for next stage
            asm volatile("s_waitcnt vmcnt(4)" ::: "memory");
        } else {
            asm volatile("s_waitcnt vmcnt(0)" ::: "memory");
        }
        __builtin_amdgcn_sched_barrier(0);
        compute(s, s & 1);
    }

    // D layout: col = lane&15 (-> o0/o1), row = q4*4 + j, per m-tile of 16
    if constexpr (PART) {
        __bf16* part = bpart + (size_t)ks * OUT_ELEMS;
        #pragma unroll
        for (int m = 0; m < 4; ++m) {
            #pragma unroll
            for (int j = 0; j < 4; ++j) {
                const int t = m * 16 + q4 * 4 + j;
                part[(size_t)t * OUT_DIM + o0] = (__bf16)acc[m][0][j];
                part[(size_t)t * OUT_DIM + o1] = (__bf16)acc[m][1][j];
            }
        }
    } else {
        #pragma unroll
        for (int m = 0; m < 4; ++m) {
            #pragma unroll
            for (int j = 0; j < 4; ++j) {
                const int t = m * 16 + q4 * 4 + j;
                unsafeAtomicAdd(&out[(size_t)t * OUT_DIM + o0], acc[m][0][j]);
                unsafeAtomicAdd(&out[(size_t)t * OUT_DIM + o1], acc[m][1][j]);
            }
        }
    }
}

extern "C" void kernel_launch(void* const* d_in, const int* in_sizes, int n_in,
                              void* d_out, int out_size, void* d_ws, size_t ws_size,
                              hipStream_t stream)
{
    const float* x      = (const float*)d_in[0];
    const int*   qw     = (const int*)d_in[1];
    const float* qrange = (const float*)d_in[2];
    const float* qmin   = (const float*)d_in[3];
    float* out = (float*)d_out;

    const size_t part_bytes = (size_t)SPLITK * OUT_ELEMS * sizeof(short); // 8MB

    if (ws_size >= PART_OFF + part_bytes) {
        __bf16* part = (__bf16*)((char*)d_ws + PART_OFF);
        qgemm<true><<<dim3(OUT_DIM / NTILE, SPLITK), dim3(512), 0, stream>>>(
            x, qw, qrange, qmin, out, part);
        const int n8 = OUT_ELEMS / 8;
        reduce_kernel<<<dim3(n8 / 256), dim3(256), 0, stream>>>(part, out, n8);
    } else {
        // fallback: atomic path (requires zeroed output)
        const int n4 = out_size / 4;
        zero_kernel<<<dim3((n4 + 255) / 256), dim3(256), 0, stream>>>((float4*)d_out, n4);
        qgemm<false><<<dim3(OUT_DIM / NTILE, SPLITK), dim3(512), 0, stream>>>(
            x, qw, qrange, qmin, out, nullptr);
    }
}